// Round 1
// baseline (196.360 us; speedup 1.0000x reference)
//
#include <hip/hip_runtime.h>

#define NSP 16384   // H*W
#define CCH 64
#define BATCH 32
#define SPLIT 4
#define CPB (CCH / SPLIT)   // 16 channels per block

#define LW 76               // LDS row stride (floats): 72 used (64+8 halo) + 4 pad; 19 quads
#define LH 40               // LDS rows: 32 + 8 halo
#define LDSF (LW * LH)      // 3040 floats (12.2 KB)
#define NQ (LDSF / 4)       // 760 quads (= 40 rows * 19 quads, exact)
#define NISS 3              // stage issues per thread

__device__ __forceinline__ void gload_lds16(const float* g, float* l) {
    __builtin_amdgcn_global_load_lds(
        (const __attribute__((address_space(1))) void*)g,
        (__attribute__((address_space(3))) void*)l,
        16, 0, 0);
}

__device__ __forceinline__ unsigned short f2bf(float f) {   // RNE
    unsigned u = __float_as_uint(f);
    u += 0x7fffu + ((u >> 16) & 1u);
    return (unsigned short)(u >> 16);
}
__device__ __forceinline__ float bflo(unsigned u) { return __uint_as_float(u << 16); }
__device__ __forceinline__ float bfhi(unsigned u) { return __uint_as_float(u & 0xffff0000u); }

// ---------------- K1: depthwise 9x9 conv + per-split t partials + channel sums ----
// Tiles: 8 per plane (2 wide x 4 tall), each 64 cols x 32 rows.
// Threads: 256 = 16x16; each thread owns 4 cols x 2 rows.
template<int YBF>
__global__ __launch_bounds__(256, 4) void conv_kernel(
    const float* __restrict__ x, const float* __restrict__ wdw,
    const float* __restrict__ bdw, const float* __restrict__ w1d,
    const float* __restrict__ zpad,
    float* __restrict__ yf, unsigned short* __restrict__ yb,
    float* __restrict__ tx_parts, float* __restrict__ ty_parts,
    float* __restrict__ S_x, float* __restrict__ S_y)
{
    const int tile = blockIdx.x;            // 0..7: 2x4 tiles of 64x32
    const int b    = blockIdx.y;
    const int sp   = blockIdx.z;            // channel split 0..3
    const int tile_cx = (tile & 1) * 64;
    const int tile_ry = (tile >> 1) * 32;
    const int tid = threadIdx.x;
    const int tx = tid & 15, ty = tid >> 4;
    const int c0 = tx * 4, r0 = ty * 2;     // 4 cols x 2 rows per thread
    const int cbase = sp * CPB;

    __shared__ float bufs[2][LDSF];

    // staging geometry: linear quad q -> (row=q/19, col4=q%19) -> global offset
    int soff[NISS]; unsigned okm = 0;
    #pragma unroll
    for (int r = 0; r < NISS; ++r) {
        int q = tid + 256 * r;
        int lrow = q / 19, lc4 = q - lrow * 19;
        int gr = tile_ry - 4 + lrow;
        int gc = tile_cx - 4 + lc4 * 4;
        soff[r] = gr * 128 + gc;
        if (q < NQ && (unsigned)gr < 128u && (unsigned)gc <= 124u) okm |= 1u << r;
    }

    const float* xb = x + (size_t)b * CCH * NSP;

#define STAGE(cc, dst) do {                                               \
        const float* plane_ = xb + (size_t)(cc) * NSP;                    \
        _Pragma("unroll")                                                 \
        for (int r_ = 0; r_ < NISS; ++r_) {                               \
            int q_ = tid + 256 * r_;                                      \
            if (q_ < NQ) {                                                \
                const float* g_ = ((okm >> r_) & 1u) ? plane_ + soff[r_]  \
                                                     : zpad;              \
                gload_lds16(g_, &(dst)[4 * q_]);                          \
            }                                                             \
        }                                                                 \
    } while (0)

    STAGE(cbase, bufs[0]);                  // prologue

    float txa[2][4] = {};
    float tya[2][4] = {};
    __syncthreads();                        // drains prologue vmcnt

    for (int k = 0; k < CPB; ++k) {
        const int c = cbase + k;
        if (k + 1 < CPB) STAGE(c + 1, bufs[(k + 1) & 1]);   // async prefetch

        const float* cb = bufs[k & 1];
        const float* wc = wdw + c * 81;     // uniform -> s_loads
        float acc[2][4] = {};
        float cx[2][4];
        const float* basep = cb + r0 * LW + c0;
        #pragma unroll
        for (int ir = 0; ir < 10; ++ir) {
            const float* row = basep + ir * LW;
            float4 A  = *(const float4*)(row);
            float4 Bv = *(const float4*)(row + 4);
            float4 Cv = *(const float4*)(row + 8);
            float v[12] = {A.x, A.y, A.z, A.w, Bv.x, Bv.y, Bv.z, Bv.w,
                           Cv.x, Cv.y, Cv.z, Cv.w};
            if (ir >= 4 && ir < 6) {
                #pragma unroll
                for (int q = 0; q < 4; ++q) cx[ir - 4][q] = v[q + 4];
            }
            #pragma unroll
            for (int tv = 0; tv < 9; ++tv) {
                int o = ir - tv;
                if (o >= 0 && o < 2) {
                    #pragma unroll
                    for (int kx = 0; kx < 9; ++kx) {
                        float w = wc[tv * 9 + kx];
                        #pragma unroll
                        for (int q = 0; q < 4; ++q) acc[o][q] += w * v[kx + q];
                    }
                }
            }
        }

        const float bias = bdw[c];
        const float w1c  = w1d[c];
        float sx = 0.f, sy = 0.f;
        const size_t ybase = (size_t)(b * CCH + c) * NSP + (tile_ry + r0) * 128 + tile_cx + c0;
        #pragma unroll
        for (int o = 0; o < 2; ++o) {
            float yv[4];
            #pragma unroll
            for (int q = 0; q < 4; ++q) {
                yv[q] = acc[o][q] + bias;
                sx += cx[o][q];
                sy += yv[q];
                txa[o][q] += w1c * cx[o][q];
                tya[o][q] += w1c * yv[q];
            }
            if (YBF) {
                ushort4 s;
                s.x = f2bf(yv[0]); s.y = f2bf(yv[1]); s.z = f2bf(yv[2]); s.w = f2bf(yv[3]);
                *(ushort4*)(yb + ybase + o * 128) = s;
            } else {
                *(float4*)(yf + ybase + o * 128) = make_float4(yv[0], yv[1], yv[2], yv[3]);
            }
        }

        #pragma unroll
        for (int off = 32; off > 0; off >>= 1) {
            sx += __shfl_down(sx, off);
            sy += __shfl_down(sy, off);
        }
        if ((tid & 63) == 0) {
            atomicAdd(&S_x[b * CCH + c], sx);
            atomicAdd(&S_y[b * CCH + c], sy);
        }
        __syncthreads();   // drains prefetch vmcnt + guards buffer reuse
    }
#undef STAGE

    const size_t tb = ((size_t)sp * BATCH + b) * NSP + (tile_ry + r0) * 128 + tile_cx + c0;
    float* txp = tx_parts + tb;
    float* typ = ty_parts + tb;
    #pragma unroll
    for (int o = 0; o < 2; ++o) {
        *(float4*)(txp + o * 128) = make_float4(txa[o][0], txa[o][1], txa[o][2], txa[o][3]);
        *(float4*)(typ + o * 128) = make_float4(tya[o][0], tya[o][1], tya[o][2], tya[o][3]);
    }
}

// ---------------- K1b: collapse split-partials into t_x, t_y ----------------------
__global__ __launch_bounds__(256) void collapse_kernel(
    const float4* __restrict__ parts, float4* __restrict__ tcoll)
{
    const int i = blockIdx.x * 256 + threadIdx.x;   // grid 1024 -> 262144
    const int tsel = i >> 17;                        // 0: t_x, 1: t_y
    const int j = i & 131071;                        // float4 idx within [32][16384]
    const float4* p = parts + (size_t)tsel * SPLIT * 131072;
    float4 s = p[j];
    #pragma unroll
    for (int r = 1; r < SPLIT; ++r) {
        float4 a = p[j + (size_t)r * 131072];
        s.x += a.x; s.y += a.y; s.z += a.z; s.w += a.w;
    }
    tcoll[(size_t)tsel * 131072 + j] = s;
}

// ---------------- K2: dot_x[b,i] = x_row . t_x ; dot_y[b,i] = y_row . t_y ---------
template<int YBF>
__global__ __launch_bounds__(256) void dot_kernel(
    const float* __restrict__ x, const float* __restrict__ yf,
    const unsigned short* __restrict__ yb,
    const float* __restrict__ t_x, const float* __restrict__ t_y,
    float* __restrict__ dot_x, float* __restrict__ dot_y)
{
    const int bc = blockIdx.x;              // 0..2047
    const int b  = bc >> 6;
    const int tid = threadIdx.x;
    const float4* xr  = (const float4*)(x   + (size_t)bc * NSP);
    const float4* txr = (const float4*)(t_x + (size_t)b * NSP);
    const float4* tyr = (const float4*)(t_y + (size_t)b * NSP);
    float dx = 0.f, dy = 0.f;
    if (YBF) {
        const uint4* yr = (const uint4*)(yb + (size_t)bc * NSP);
        for (int i = tid; i < NSP / 8; i += 256) {
            float4 x0 = xr[2 * i], x1 = xr[2 * i + 1];
            float4 t0 = txr[2 * i], t1 = txr[2 * i + 1];
            float4 u0 = tyr[2 * i], u1 = tyr[2 * i + 1];
            uint4 yv = yr[i];
            dx += x0.x * t0.x + x0.y * t0.y + x0.z * t0.z + x0.w * t0.w
                + x1.x * t1.x + x1.y * t1.y + x1.z * t1.z + x1.w * t1.w;
            dy += bflo(yv.x) * u0.x + bfhi(yv.x) * u0.y
                + bflo(yv.y) * u0.z + bfhi(yv.y) * u0.w
                + bflo(yv.z) * u1.x + bfhi(yv.z) * u1.y
                + bflo(yv.w) * u1.z + bfhi(yv.w) * u1.w;
        }
    } else {
        const float4* yr = (const float4*)(yf + (size_t)bc * NSP);
        for (int i = tid; i < NSP / 4; i += 256) {
            float4 xv = xr[i], tv = txr[i];
            float4 yv = yr[i], uv = tyr[i];
            dx += xv.x * tv.x + xv.y * tv.y + xv.z * tv.z + xv.w * tv.w;
            dy += yv.x * uv.x + yv.y * uv.y + yv.z * uv.z + yv.w * uv.w;
        }
    }
    #pragma unroll
    for (int off = 32; off > 0; off >>= 1) {
        dx += __shfl_down(dx, off);
        dy += __shfl_down(dy, off);
    }
    __shared__ float red[8];
    const int wid = tid >> 6;
    if ((tid & 63) == 0) { red[wid * 2] = dx; red[wid * 2 + 1] = dy; }
    __syncthreads();
    if (tid == 0) {
        dot_x[bc] = red[0] + red[2] + red[4] + red[6];
        dot_y[bc] = red[1] + red[3] + red[5] + red[7];
    }
}

// ---------------- K3: c, c_, softmax, att  (Tsum via w1d . S identity) ------------
__global__ __launch_bounds__(64) void att_kernel(
    const float* __restrict__ S_x, const float* __restrict__ S_y,
    const float* __restrict__ dot_x, const float* __restrict__ dot_y,
    const float* __restrict__ w1d, const float* __restrict__ b1d,
    float* __restrict__ att)
{
    const int b = blockIdx.x;
    const int c = threadIdx.x;              // 0..63
    const float sx = S_x[b * CCH + c];
    const float sy = S_y[b * CCH + c];
    const float w  = w1d[c];
    float tsx = w * sx, tsy = w * sy;
    #pragma unroll
    for (int off = 32; off > 0; off >>= 1) {
        tsx += __shfl_xor(tsx, off);
        tsy += __shfl_xor(tsy, off);
    }
    const float inv_n  = 1.f / 16384.f;
    const float inv_n1 = 1.f / 16383.f;
    const float bb = b1d[0];
    float cxv = (dot_x[b * CCH + c] - sx * inv_n * tsx) * inv_n1 + bb;
    float cyv = (dot_y[b * CCH + c] - sy * inv_n * tsy) * inv_n1 + bb;
    float d = cyv - cxv;
    float m = d;
    #pragma unroll
    for (int off = 32; off > 0; off >>= 1) m = fmaxf(m, __shfl_xor(m, off));
    float e = __expf(d - m);
    float s = e;
    #pragma unroll
    for (int off = 32; off > 0; off >>= 1) s += __shfl_xor(s, off);
    float r = e / s;
    float a = cyv * (1.f + r);
    att[b * CCH + c] = 1.f / (1.f + __expf(-a));
}

// ---------------- K4: out = y * att -----------------------------------------------
template<int YBF>
__global__ __launch_bounds__(256) void scale_kernel(
    const unsigned short* __restrict__ yb, float* __restrict__ out,
    const float* __restrict__ att)
{
    const size_t total8 = (size_t)BATCH * CCH * NSP / 8;
    size_t i = (size_t)blockIdx.x * blockDim.x + threadIdx.x;
    const size_t stride = (size_t)gridDim.x * blockDim.x;
    if (YBF) {
        for (; i < total8; i += stride) {
            uint4 y = ((const uint4*)yb)[i];
            float a = att[(i * 8) >> 14];
            float4 o0 = make_float4(bflo(y.x) * a, bfhi(y.x) * a,
                                    bflo(y.y) * a, bfhi(y.y) * a);
            float4 o1 = make_float4(bflo(y.z) * a, bfhi(y.z) * a,
                                    bflo(y.w) * a, bfhi(y.w) * a);
            ((float4*)out)[2 * i]     = o0;
            ((float4*)out)[2 * i + 1] = o1;
        }
    } else {
        for (; i < total8; i += stride) {
            float a = att[(i * 8) >> 14];
            float4 v0 = ((const float4*)out)[2 * i];
            float4 v1 = ((const float4*)out)[2 * i + 1];
            v0.x *= a; v0.y *= a; v0.z *= a; v0.w *= a;
            v1.x *= a; v1.y *= a; v1.z *= a; v1.w *= a;
            ((float4*)out)[2 * i]     = v0;
            ((float4*)out)[2 * i + 1] = v1;
        }
    }
}

extern "C" void kernel_launch(void* const* d_in, const int* in_sizes, int n_in,
                              void* d_out, int out_size, void* d_ws, size_t ws_size,
                              hipStream_t stream) {
    const float* x   = (const float*)d_in[0];
    const float* w1d = (const float*)d_in[1];
    const float* b1d = (const float*)d_in[2];
    const float* wdw = (const float*)d_in[3];
    const float* bdw = (const float*)d_in[4];
    float* out = (float*)d_out;
    float* fw  = (float*)d_ws;

    // float workspace layout
    const size_t PARTS = (size_t)SPLIT * BATCH * NSP;       // 2,097,152 floats
    float* tx_parts = fw;
    float* ty_parts = tx_parts + PARTS;
    float* t_x      = ty_parts + PARTS;
    float* t_y      = t_x + (size_t)BATCH * NSP;
    float* S_x      = t_y + (size_t)BATCH * NSP;
    float* S_y      = S_x + 2048;
    float* dot_x    = S_y + 2048;
    float* dot_y    = dot_x + 2048;
    float* att      = dot_y + 2048;
    float* zpad     = att + 2048;                           // 64 floats
    float* fend     = zpad + 64;
    size_t fbytes   = (size_t)((char*)fend - (char*)fw);
    fbytes = (fbytes + 255) & ~(size_t)255;
    unsigned short* yb = (unsigned short*)((char*)d_ws + fbytes);
    const size_t yb_bytes = (size_t)BATCH * CCH * NSP * 2;  // 67.1 MB

    const bool ybf = (ws_size >= fbytes + yb_bytes);

    hipMemsetAsync(S_x, 0, 2 * 2048 * sizeof(float), stream);
    hipMemsetAsync(zpad, 0, 64 * sizeof(float), stream);

    if (ybf) {
        conv_kernel<1><<<dim3(8, BATCH, SPLIT), 256, 0, stream>>>(
            x, wdw, bdw, w1d, zpad, out, yb, tx_parts, ty_parts, S_x, S_y);
        collapse_kernel<<<1024, 256, 0, stream>>>((const float4*)tx_parts, (float4*)t_x);
        dot_kernel<1><<<2048, 256, 0, stream>>>(x, out, yb, t_x, t_y, dot_x, dot_y);
        att_kernel<<<BATCH, 64, 0, stream>>>(S_x, S_y, dot_x, dot_y, w1d, b1d, att);
        scale_kernel<1><<<2048, 256, 0, stream>>>(yb, out, att);
    } else {
        conv_kernel<0><<<dim3(8, BATCH, SPLIT), 256, 0, stream>>>(
            x, wdw, bdw, w1d, zpad, out, yb, tx_parts, ty_parts, S_x, S_y);
        collapse_kernel<<<1024, 256, 0, stream>>>((const float4*)tx_parts, (float4*)t_x);
        dot_kernel<0><<<2048, 256, 0, stream>>>(x, out, yb, t_x, t_y, dot_x, dot_y);
        att_kernel<<<BATCH, 64, 0, stream>>>(S_x, S_y, dot_x, dot_y, w1d, b1d, att);
        scale_kernel<0><<<2048, 256, 0, stream>>>(yb, out, att);
    }
}

// Round 2
// 180.913 us; speedup vs baseline: 1.0854x; 1.0854x over previous
//
#include <hip/hip_runtime.h>

#define NSP 16384   // H*W
#define CCH 64
#define BATCH 32
#define SPLIT 4
#define CPB (CCH / SPLIT)   // 16 channels per block

// LDS tile: full-width strip. 34 used quads/row (136 cols: 128 + 8 halo), pad to 40.
#define LW 160              // words per LDS row (40 quads)
#define LH 40               // rows: 32 + 8 halo
#define LDSF (LW * LH)      // 6400 floats (25.6 KB per buffer)
#define NQ (LDSF / 4)       // 1600 quads
#define NISS 7              // ceil(1600/256); last issue only tid<64

__device__ __forceinline__ void gload_lds16(const float* g, float* l) {
    __builtin_amdgcn_global_load_lds(
        (const __attribute__((address_space(1))) void*)g,
        (__attribute__((address_space(3))) void*)l,
        16, 0, 0);
}

// quad-column swizzle: bijective involution on 0..39, spreads W=8 read pattern
// across all 8 bank-groups (2 words/bank per quarter-wave = minimal).
__device__ __forceinline__ int swq(int q) { return q ^ ((q >> 3) & 7); }

__device__ __forceinline__ unsigned short f2bf(float f) {   // RNE
    unsigned u = __float_as_uint(f);
    u += 0x7fffu + ((u >> 16) & 1u);
    return (unsigned short)(u >> 16);
}
__device__ __forceinline__ float bflo(unsigned u) { return __uint_as_float(u << 16); }
__device__ __forceinline__ float bfhi(unsigned u) { return __uint_as_float(u & 0xffff0000u); }

// ---------------- K1: depthwise 9x9 conv + per-split t partials + channel sums ----
// Tiles: 4 per plane, each full-width 128 cols x 32 rows.
// Threads: 256 = 16x16; each thread owns 8 cols x 2 rows (W=8 -> 6:1 VALU:LDS).
template<int YBF>
__global__ __launch_bounds__(256, 2) void conv_kernel(
    const float* __restrict__ x, const float* __restrict__ wdw,
    const float* __restrict__ bdw, const float* __restrict__ w1d,
    const float* __restrict__ zpad,
    float* __restrict__ yf, unsigned short* __restrict__ yb,
    float* __restrict__ tx_parts, float* __restrict__ ty_parts,
    float* __restrict__ S_x, float* __restrict__ S_y)
{
    const int tile = blockIdx.x;            // 0..3: 32-row strips
    const int b    = blockIdx.y;
    const int sp   = blockIdx.z;            // channel split 0..3
    const int tile_ry = tile * 32;
    const int tid = threadIdx.x;
    const int tx = tid & 15, ty = tid >> 4;
    const int c0 = tx * 8, r0 = ty * 2;     // 8 cols x 2 rows per thread
    const int cbase = sp * CPB;

    __shared__ float bufs[2][LDSF];

    // staging geometry: LDS quad Q holds global quad swq(Q%40) of row Q/40
    int soff[NISS]; unsigned okm = 0;
    #pragma unroll
    for (int r = 0; r < NISS; ++r) {
        int q = tid + 256 * r;
        int lrow = q / 40, qcl = q - lrow * 40;
        int gq = swq(qcl);                  // global quad col (0 -> col -4)
        int gr = tile_ry - 4 + lrow;
        int gc = gq * 4 - 4;
        soff[r] = gr * 128 + gc;
        if (q < NQ && (unsigned)gr < 128u && gq >= 1 && gq <= 32) okm |= 1u << r;
    }

    // per-thread swizzled read base offsets (words), one per 16B column chunk
    int rb[4];
    #pragma unroll
    for (int j = 0; j < 4; ++j) rb[j] = r0 * LW + swq(2 * tx + j) * 4;

    const float* xb = x + (size_t)b * CCH * NSP;

#define STAGE(cc, dst) do {                                               \
        const float* plane_ = xb + (size_t)(cc) * NSP;                    \
        _Pragma("unroll")                                                 \
        for (int r_ = 0; r_ < NISS; ++r_) {                               \
            int q_ = tid + 256 * r_;                                      \
            if (q_ < NQ) {                                                \
                const float* g_ = ((okm >> r_) & 1u) ? plane_ + soff[r_]  \
                                                     : zpad;              \
                gload_lds16(g_, &(dst)[4 * q_]);                          \
            }                                                             \
        }                                                                 \
    } while (0)

    STAGE(cbase, bufs[0]);                  // prologue

    float txa[2][8] = {};
    float tya[2][8] = {};
    __syncthreads();                        // drains prologue vmcnt

    for (int k = 0; k < CPB; ++k) {
        const int c = cbase + k;
        if (k + 1 < CPB) STAGE(c + 1, bufs[(k + 1) & 1]);   // async prefetch

        const float* cb = bufs[k & 1];
        const float* wc = wdw + c * 81;     // uniform -> s_loads
        float acc[2][8] = {};
        float cx[2][8];
        #pragma unroll
        for (int ir = 0; ir < 10; ++ir) {
            float4 f0 = *(const float4*)(cb + rb[0] + ir * LW);
            float4 f1 = *(const float4*)(cb + rb[1] + ir * LW);
            float4 f2 = *(const float4*)(cb + rb[2] + ir * LW);
            float4 f3 = *(const float4*)(cb + rb[3] + ir * LW);
            float v[16] = {f0.x, f0.y, f0.z, f0.w, f1.x, f1.y, f1.z, f1.w,
                           f2.x, f2.y, f2.z, f2.w, f3.x, f3.y, f3.z, f3.w};
            if (ir == 4) {
                #pragma unroll
                for (int q = 0; q < 8; ++q) cx[0][q] = v[q + 4];
            }
            if (ir == 5) {
                #pragma unroll
                for (int q = 0; q < 8; ++q) cx[1][q] = v[q + 4];
            }
            #pragma unroll
            for (int o = 0; o < 2; ++o) {
                int tv = ir - o;
                if (tv >= 0 && tv <= 8) {
                    #pragma unroll
                    for (int kx = 0; kx < 9; ++kx) {
                        float w = wc[tv * 9 + kx];
                        #pragma unroll
                        for (int q = 0; q < 8; ++q) acc[o][q] += w * v[kx + q];
                    }
                }
            }
        }

        const float bias = bdw[c];
        const float w1c  = w1d[c];
        float sx = 0.f, sy = 0.f;
        const size_t ybase = (size_t)(b * CCH + c) * NSP + (tile_ry + r0) * 128 + c0;
        #pragma unroll
        for (int o = 0; o < 2; ++o) {
            float yv[8];
            #pragma unroll
            for (int q = 0; q < 8; ++q) {
                yv[q] = acc[o][q] + bias;
                sx += cx[o][q];
                sy += yv[q];
                txa[o][q] += w1c * cx[o][q];
                tya[o][q] += w1c * yv[q];
            }
            if (YBF) {
                uint4 s;
                s.x = (unsigned)f2bf(yv[0]) | ((unsigned)f2bf(yv[1]) << 16);
                s.y = (unsigned)f2bf(yv[2]) | ((unsigned)f2bf(yv[3]) << 16);
                s.z = (unsigned)f2bf(yv[4]) | ((unsigned)f2bf(yv[5]) << 16);
                s.w = (unsigned)f2bf(yv[6]) | ((unsigned)f2bf(yv[7]) << 16);
                *(uint4*)(yb + ybase + o * 128) = s;
            } else {
                *(float4*)(yf + ybase + o * 128) =
                    make_float4(yv[0], yv[1], yv[2], yv[3]);
                *(float4*)(yf + ybase + o * 128 + 4) =
                    make_float4(yv[4], yv[5], yv[6], yv[7]);
            }
        }

        #pragma unroll
        for (int off = 32; off > 0; off >>= 1) {
            sx += __shfl_down(sx, off);
            sy += __shfl_down(sy, off);
        }
        if ((tid & 63) == 0) {
            atomicAdd(&S_x[b * CCH + c], sx);
            atomicAdd(&S_y[b * CCH + c], sy);
        }
        __syncthreads();   // drains prefetch vmcnt + guards buffer reuse
    }
#undef STAGE

    const size_t tb = ((size_t)sp * BATCH + b) * NSP + (tile_ry + r0) * 128 + c0;
    float* txp = tx_parts + tb;
    float* typ = ty_parts + tb;
    #pragma unroll
    for (int o = 0; o < 2; ++o) {
        *(float4*)(txp + o * 128)     = make_float4(txa[o][0], txa[o][1], txa[o][2], txa[o][3]);
        *(float4*)(txp + o * 128 + 4) = make_float4(txa[o][4], txa[o][5], txa[o][6], txa[o][7]);
        *(float4*)(typ + o * 128)     = make_float4(tya[o][0], tya[o][1], tya[o][2], tya[o][3]);
        *(float4*)(typ + o * 128 + 4) = make_float4(tya[o][4], tya[o][5], tya[o][6], tya[o][7]);
    }
}

// ---------------- K1b: collapse split-partials into t_x, t_y ----------------------
__global__ __launch_bounds__(256) void collapse_kernel(
    const float4* __restrict__ parts, float4* __restrict__ tcoll)
{
    const int i = blockIdx.x * 256 + threadIdx.x;   // grid 1024 -> 262144
    const int tsel = i >> 17;                        // 0: t_x, 1: t_y
    const int j = i & 131071;                        // float4 idx within [32][16384]
    const float4* p = parts + (size_t)tsel * SPLIT * 131072;
    float4 s = p[j];
    #pragma unroll
    for (int r = 1; r < SPLIT; ++r) {
        float4 a = p[j + (size_t)r * 131072];
        s.x += a.x; s.y += a.y; s.z += a.z; s.w += a.w;
    }
    tcoll[(size_t)tsel * 131072 + j] = s;
}

// ---------------- K2: dot_x[b,i] = x_row . t_x ; dot_y[b,i] = y_row . t_y ---------
template<int YBF>
__global__ __launch_bounds__(256) void dot_kernel(
    const float* __restrict__ x, const float* __restrict__ yf,
    const unsigned short* __restrict__ yb,
    const float* __restrict__ t_x, const float* __restrict__ t_y,
    float* __restrict__ dot_x, float* __restrict__ dot_y)
{
    const int bc = blockIdx.x;              // 0..2047
    const int b  = bc >> 6;
    const int tid = threadIdx.x;
    const float4* xr  = (const float4*)(x   + (size_t)bc * NSP);
    const float4* txr = (const float4*)(t_x + (size_t)b * NSP);
    const float4* tyr = (const float4*)(t_y + (size_t)b * NSP);
    float dx = 0.f, dy = 0.f;
    if (YBF) {
        const uint4* yr = (const uint4*)(yb + (size_t)bc * NSP);
        for (int i = tid; i < NSP / 8; i += 256) {
            float4 x0 = xr[2 * i], x1 = xr[2 * i + 1];
            float4 t0 = txr[2 * i], t1 = txr[2 * i + 1];
            float4 u0 = tyr[2 * i], u1 = tyr[2 * i + 1];
            uint4 yv = yr[i];
            dx += x0.x * t0.x + x0.y * t0.y + x0.z * t0.z + x0.w * t0.w
                + x1.x * t1.x + x1.y * t1.y + x1.z * t1.z + x1.w * t1.w;
            dy += bflo(yv.x) * u0.x + bfhi(yv.x) * u0.y
                + bflo(yv.y) * u0.z + bfhi(yv.y) * u0.w
                + bflo(yv.z) * u1.x + bfhi(yv.z) * u1.y
                + bflo(yv.w) * u1.z + bfhi(yv.w) * u1.w;
        }
    } else {
        const float4* yr = (const float4*)(yf + (size_t)bc * NSP);
        for (int i = tid; i < NSP / 4; i += 256) {
            float4 xv = xr[i], tv = txr[i];
            float4 yv = yr[i], uv = tyr[i];
            dx += xv.x * tv.x + xv.y * tv.y + xv.z * tv.z + xv.w * tv.w;
            dy += yv.x * uv.x + yv.y * uv.y + yv.z * uv.z + yv.w * uv.w;
        }
    }
    #pragma unroll
    for (int off = 32; off > 0; off >>= 1) {
        dx += __shfl_down(dx, off);
        dy += __shfl_down(dy, off);
    }
    __shared__ float red[8];
    const int wid = tid >> 6;
    if ((tid & 63) == 0) { red[wid * 2] = dx; red[wid * 2 + 1] = dy; }
    __syncthreads();
    if (tid == 0) {
        dot_x[bc] = red[0] + red[2] + red[4] + red[6];
        dot_y[bc] = red[1] + red[3] + red[5] + red[7];
    }
}

// ---------------- K3: c, c_, softmax, att  (Tsum via w1d . S identity) ------------
__global__ __launch_bounds__(64) void att_kernel(
    const float* __restrict__ S_x, const float* __restrict__ S_y,
    const float* __restrict__ dot_x, const float* __restrict__ dot_y,
    const float* __restrict__ w1d, const float* __restrict__ b1d,
    float* __restrict__ att)
{
    const int b = blockIdx.x;
    const int c = threadIdx.x;              // 0..63
    const float sx = S_x[b * CCH + c];
    const float sy = S_y[b * CCH + c];
    const float w  = w1d[c];
    float tsx = w * sx, tsy = w * sy;
    #pragma unroll
    for (int off = 32; off > 0; off >>= 1) {
        tsx += __shfl_xor(tsx, off);
        tsy += __shfl_xor(tsy, off);
    }
    const float inv_n  = 1.f / 16384.f;
    const float inv_n1 = 1.f / 16383.f;
    const float bb = b1d[0];
    float cxv = (dot_x[b * CCH + c] - sx * inv_n * tsx) * inv_n1 + bb;
    float cyv = (dot_y[b * CCH + c] - sy * inv_n * tsy) * inv_n1 + bb;
    float d = cyv - cxv;
    float m = d;
    #pragma unroll
    for (int off = 32; off > 0; off >>= 1) m = fmaxf(m, __shfl_xor(m, off));
    float e = __expf(d - m);
    float s = e;
    #pragma unroll
    for (int off = 32; off > 0; off >>= 1) s += __shfl_xor(s, off);
    float r = e / s;
    float a = cyv * (1.f + r);
    att[b * CCH + c] = 1.f / (1.f + __expf(-a));
}

// ---------------- K4: out = y * att -----------------------------------------------
template<int YBF>
__global__ __launch_bounds__(256) void scale_kernel(
    const unsigned short* __restrict__ yb, float* __restrict__ out,
    const float* __restrict__ att)
{
    const size_t total8 = (size_t)BATCH * CCH * NSP / 8;
    size_t i = (size_t)blockIdx.x * blockDim.x + threadIdx.x;
    const size_t stride = (size_t)gridDim.x * blockDim.x;
    if (YBF) {
        for (; i < total8; i += stride) {
            uint4 y = ((const uint4*)yb)[i];
            float a = att[(i * 8) >> 14];
            float4 o0 = make_float4(bflo(y.x) * a, bfhi(y.x) * a,
                                    bflo(y.y) * a, bfhi(y.y) * a);
            float4 o1 = make_float4(bflo(y.z) * a, bfhi(y.z) * a,
                                    bflo(y.w) * a, bfhi(y.w) * a);
            ((float4*)out)[2 * i]     = o0;
            ((float4*)out)[2 * i + 1] = o1;
        }
    } else {
        for (; i < total8; i += stride) {
            float a = att[(i * 8) >> 14];
            float4 v0 = ((const float4*)out)[2 * i];
            float4 v1 = ((const float4*)out)[2 * i + 1];
            v0.x *= a; v0.y *= a; v0.z *= a; v0.w *= a;
            v1.x *= a; v1.y *= a; v1.z *= a; v1.w *= a;
            ((float4*)out)[2 * i]     = v0;
            ((float4*)out)[2 * i + 1] = v1;
        }
    }
}

extern "C" void kernel_launch(void* const* d_in, const int* in_sizes, int n_in,
                              void* d_out, int out_size, void* d_ws, size_t ws_size,
                              hipStream_t stream) {
    const float* x   = (const float*)d_in[0];
    const float* w1d = (const float*)d_in[1];
    const float* b1d = (const float*)d_in[2];
    const float* wdw = (const float*)d_in[3];
    const float* bdw = (const float*)d_in[4];
    float* out = (float*)d_out;
    float* fw  = (float*)d_ws;

    // float workspace layout
    const size_t PARTS = (size_t)SPLIT * BATCH * NSP;       // 2,097,152 floats
    float* tx_parts = fw;
    float* ty_parts = tx_parts + PARTS;
    float* t_x      = ty_parts + PARTS;
    float* t_y      = t_x + (size_t)BATCH * NSP;
    float* S_x      = t_y + (size_t)BATCH * NSP;
    float* S_y      = S_x + 2048;
    float* dot_x    = S_y + 2048;
    float* dot_y    = dot_x + 2048;
    float* att      = dot_y + 2048;
    float* zpad     = att + 2048;                           // 64 floats
    float* fend     = zpad + 64;
    size_t fbytes   = (size_t)((char*)fend - (char*)fw);
    fbytes = (fbytes + 255) & ~(size_t)255;
    unsigned short* yb = (unsigned short*)((char*)d_ws + fbytes);
    const size_t yb_bytes = (size_t)BATCH * CCH * NSP * 2;  // 67.1 MB

    const bool ybf = (ws_size >= fbytes + yb_bytes);

    hipMemsetAsync(S_x, 0, 2 * 2048 * sizeof(float), stream);
    hipMemsetAsync(zpad, 0, 64 * sizeof(float), stream);

    if (ybf) {
        conv_kernel<1><<<dim3(4, BATCH, SPLIT), 256, 0, stream>>>(
            x, wdw, bdw, w1d, zpad, out, yb, tx_parts, ty_parts, S_x, S_y);
        collapse_kernel<<<1024, 256, 0, stream>>>((const float4*)tx_parts, (float4*)t_x);
        dot_kernel<1><<<2048, 256, 0, stream>>>(x, out, yb, t_x, t_y, dot_x, dot_y);
        att_kernel<<<BATCH, 64, 0, stream>>>(S_x, S_y, dot_x, dot_y, w1d, b1d, att);
        scale_kernel<1><<<2048, 256, 0, stream>>>(yb, out, att);
    } else {
        conv_kernel<0><<<dim3(4, BATCH, SPLIT), 256, 0, stream>>>(
            x, wdw, bdw, w1d, zpad, out, yb, tx_parts, ty_parts, S_x, S_y);
        collapse_kernel<<<1024, 256, 0, stream>>>((const float4*)tx_parts, (float4*)t_x);
        dot_kernel<0><<<2048, 256, 0, stream>>>(x, out, yb, t_x, t_y, dot_x, dot_y);
        att_kernel<<<BATCH, 64, 0, stream>>>(S_x, S_y, dot_x, dot_y, w1d, b1d, att);
        scale_kernel<0><<<2048, 256, 0, stream>>>(yb, out, att);
    }
}